// Round 12
// baseline (201.375 us; speedup 1.0000x reference)
//
#include <hip/hip_runtime.h>
#include <math.h>

#define DIM 768
#define NHEADS 12
#define HD 64
#define BB 2
#define LL 2048
#define M_TOT (BB*LL)      /* 4096 */
#define NQKV (3*DIM)       /* 2304 */
#define QSCALE 0.18033688011112042f  /* 0.125 * log2(e) */

typedef __attribute__((ext_vector_type(8))) short short8;
typedef __attribute__((ext_vector_type(4))) float floatx4;

__device__ __forceinline__ unsigned short f2bf(float f) {
  unsigned int u = __float_as_uint(f);
  u += 0x7fff + ((u >> 16) & 1);   // round-to-nearest-even
  return (unsigned short)(u >> 16);
}

#if __has_builtin(__builtin_amdgcn_cvt_pk_bf16_f32)
typedef __attribute__((ext_vector_type(2))) __bf16 bf16x2_t;
__device__ __forceinline__ unsigned int pack2bf(float a, float b) {
  bf16x2_t r = __builtin_amdgcn_cvt_pk_bf16_f32(a, b);   // lo=a, hi=b, RNE
  return *(unsigned int*)&r;
}
#else
__device__ __forceinline__ unsigned int pack2bf(float a, float b) {
  unsigned int ua = __float_as_uint(a) + 0x8000u;
  unsigned int ub = __float_as_uint(b) + 0x8000u;
  return (ub & 0xffff0000u) | (ua >> 16);
}
#endif

// bare v_exp_f32 (scores bounded, no denormal/NaN risk) — avoids OCML fixups
#if __has_builtin(__builtin_amdgcn_exp2f)
#define EXP2(x) __builtin_amdgcn_exp2f(x)
#else
#define EXP2(x) exp2f(x)
#endif

// async global->LDS DMA, 16B/lane; LDS dst = wave-uniform base + lane*16
__device__ __forceinline__ void load_lds16(const unsigned short* g, unsigned short* l) {
  __builtin_amdgcn_global_load_lds(
      (const __attribute__((address_space(1))) unsigned int*)g,
      (__attribute__((address_space(3))) unsigned int*)l, 16, 0, 0);
}

// ---- prep: transpose-cast BOTH weights in one launch ----
__global__ void prep_kernel(const float* __restrict__ Wqkv, const float* __restrict__ Wproj,
                            unsigned short* __restrict__ wqkv_t,
                            unsigned short* __restrict__ wproj_t) {
  __shared__ float tl[32][33];
  int bx = blockIdx.x;
  const float* src; unsigned short* dst; int C, r0, c0;
  if (bx < 1728) { src = Wqkv;  dst = wqkv_t;  C = NQKV; c0 = (bx % 72) * 32; r0 = (bx / 72) * 32; }
  else { int b2 = bx - 1728; src = Wproj; dst = wproj_t; C = DIM; c0 = (b2 % 24) * 32; r0 = (b2 / 24) * 32; }
  int t = threadIdx.x;
  int tr = t >> 3, tc = (t & 7) * 4;
  float4 v = *(const float4*)&src[(size_t)(r0 + tr) * C + c0 + tc];
  tl[tr][tc] = v.x; tl[tr][tc + 1] = v.y; tl[tr][tc + 2] = v.z; tl[tr][tc + 3] = v.w;
  __syncthreads();
  int oc = t >> 3, orr = (t & 7) * 4;
  ushort4 o;
  o.x = f2bf(tl[orr][oc]); o.y = f2bf(tl[orr + 1][oc]);
  o.z = f2bf(tl[orr + 2][oc]); o.w = f2bf(tl[orr + 3][oc]);
  *(ushort4*)&dst[(size_t)(c0 + oc) * 768 + r0 + orr] = o;
}

// ---- TMxTN-tile bf16 MFMA GEMM, K=768, padded LDS (R2..R11-verified core) ----
// Inner loop / staging pattern / fusions UNTOUCHED from R11; only TM/TN are
// parameters now. R11 counters: QKV Occupancy 12% (2.25 blocks/CU), proj 0.75
// blocks/CU — both latency-bound, so halve TM (and TN for proj) to 2x-4x the
// block count. 1-D grid, m_idx = bx % NB_M (NB_M % 8 == 0 -> n-blocks sharing
// an A-slab co-XCD: A L2-resident, B streamed once per XCD).
// MODE 0: A = x fp32 (cast fused); epilogue scatters q (pre-scaled), k, and V
//         transposed into vt[bh][d][j]. MODE 1: A = opart; staging fuses the
//         split-j combine (k-tile == head -> h = kt); epilogue fp32 out + bias.
template<int TM, int TN, int MODE>
__global__ __launch_bounds__(256) void gemm_kernel(
    const float* __restrict__ Af, const unsigned short* __restrict__ Bt,
    const float* __restrict__ bias, float* __restrict__ outf,
    unsigned short* __restrict__ qb, unsigned short* __restrict__ kb,
    unsigned short* __restrict__ vtb, const float* __restrict__ lpart) {
  __shared__ unsigned short sA[TM * 72];
  __shared__ unsigned short sB[TN * 72];
  constexpr int NB_M = M_TOT / TM;       // 64 for TM=64: % 8 == 0 (XCD swizzle)
  constexpr int MT = TM / 32, NT = TN / 32;
  int t = threadIdx.x;
  int bx = blockIdx.x;
  int m0 = (bx % NB_M) * TM, n0 = (bx / NB_M) * TN;
  int wave = t >> 6, lane = t & 63, ln = lane & 15, quad = lane >> 4;
  int wm = (wave >> 1) * (TM / 2), wn = (wave & 1) * (TN / 2);
  floatx4 acc[MT][NT] = {};
  for (int kt = 0; kt < 12; ++kt) {
    __syncthreads();
#pragma unroll
    for (int p = 0; p < TM / 32; ++p) {
      int u = t + p * 256;
      int row = u >> 3, c = (u & 7) * 8;
      uint4 pk;
      if (MODE == 0) {
        const float* s = &Af[(size_t)(m0 + row) * 768 + kt * 64 + c];
        float4 v0 = *(const float4*)s, v1 = *(const float4*)(s + 4);
        pk.x = pack2bf(v0.x, v0.y); pk.y = pack2bf(v0.z, v0.w);
        pk.z = pack2bf(v1.x, v1.y); pk.w = pack2bf(v1.z, v1.w);
      } else {
        int gr = m0 + row;
        const float* s0 = &Af[(size_t)gr * 768 + kt * 64 + c];
        const float* s1 = s0 + (size_t)M_TOT * DIM;
        float4 a0 = *(const float4*)s0, a1 = *(const float4*)(s0 + 4);
        float4 b0 = *(const float4*)s1, b1 = *(const float4*)(s1 + 4);
        int bb = gr >> 11, ii = gr & 2047, bh = bb * NHEADS + kt;   // h == kt
        float inv = 1.0f / (lpart[(size_t)bh * LL + ii] +
                            lpart[(size_t)(BB * NHEADS + bh) * LL + ii]);
        pk.x = pack2bf((a0.x + b0.x) * inv, (a0.y + b0.y) * inv);
        pk.y = pack2bf((a0.z + b0.z) * inv, (a0.w + b0.w) * inv);
        pk.z = pack2bf((a1.x + b1.x) * inv, (a1.y + b1.y) * inv);
        pk.w = pack2bf((a1.z + b1.z) * inv, (a1.w + b1.w) * inv);
      }
      *(uint4*)&sA[row * 72 + c] = pk;
    }
#pragma unroll
    for (int p = 0; p < TN / 32; ++p) {
      int u = t + p * 256;
      int row = u >> 3, c = (u & 7) * 8;
      *(uint4*)&sB[row * 72 + c] = *(const uint4*)&Bt[(size_t)(n0 + row) * 768 + kt * 64 + c];
    }
    __syncthreads();
#pragma unroll
    for (int ks = 0; ks < 2; ++ks) {
      short8 af[MT], bfr[NT];
#pragma unroll
      for (int s = 0; s < MT; ++s)
        af[s] = *(const short8*)&sA[(wm + s * 16 + ln) * 72 + ks * 32 + quad * 8];
#pragma unroll
      for (int s = 0; s < NT; ++s)
        bfr[s] = *(const short8*)&sB[(wn + s * 16 + ln) * 72 + ks * 32 + quad * 8];
#pragma unroll
      for (int i = 0; i < MT; ++i)
#pragma unroll
        for (int j = 0; j < NT; ++j)
          acc[i][j] = __builtin_amdgcn_mfma_f32_16x16x32_bf16(af[i], bfr[j], acc[i][j], 0, 0, 0);
    }
  }
#pragma unroll
  for (int mt = 0; mt < MT; ++mt)
#pragma unroll
    for (int nt = 0; nt < NT; ++nt)
#pragma unroll
      for (int r = 0; r < 4; ++r) {
        int row = m0 + wm + mt * 16 + quad * 4 + r;   // C/D: col=lane&15, row=quad*4+reg
        int col = n0 + wn + nt * 16 + ln;
        float val = acc[mt][nt][r] + bias[col];
        if (MODE == 0) {
          int which = (col >= 1536) ? 2 : (col >= 768) ? 1 : 0;
          int rem = col - which * 768;
          int h = rem >> 6, d = rem & 63;
          int b = row >> 11, i = row & 2047;
          int bh = b * NHEADS + h;
          if (which == 0) qb[((size_t)bh * LL + i) * HD + d] = f2bf(val * QSCALE);
          else if (which == 1) kb[((size_t)bh * LL + i) * HD + d] = f2bf(val);
          else vtb[((size_t)bh * HD + d) * LL + i] = f2bf(val);   // transposed V
        } else {
          outf[(size_t)row * 768 + col] = val;
        }
      }
}

// ---------------- flash attention v11 (R11-verified, unchanged) ----------------
__global__ __launch_bounds__(256, 3) void flash11_kernel(
    const unsigned short* __restrict__ q, const unsigned short* __restrict__ k,
    const unsigned short* __restrict__ vt, float* __restrict__ opart,
    float* __restrict__ lpart) {
  __shared__ unsigned short sK[2][8 * 512];
  __shared__ unsigned short sV[2][8 * 512];
  __shared__ unsigned short sP[4][4 * 512];
  int t = threadIdx.x;
  int wave = t >> 6, lane = t & 63, ln = lane & 15, quad = lane >> 4;
  int bx = blockIdx.x;
  int bhjs = bx % 48;
  int i0 = (bx / 48) * 128;
  int bh = bhjs >> 1, js = bhjs & 1;
  int b = bh / NHEADS, h = bh % NHEADS;
  const unsigned short* qb = q + (size_t)bh * LL * HD;
  const unsigned short* kb = k + (size_t)bh * LL * HD;
  const unsigned short* vtb = vt + (size_t)bh * HD * LL;
  int iw0 = wave * 32;
  short8 qfrag[2][2];
#pragma unroll
  for (int si = 0; si < 2; ++si)
#pragma unroll
    for (int ks = 0; ks < 2; ++ks)
      qfrag[si][ks] = *(const short8*)&qb[(size_t)(i0 + iw0 + si * 16 + ln) * HD + ks * 32 + quad * 8];
  unsigned short* sPw = sP[wave];
  float l[2] = {0.f, 0.f};
  floatx4 oacc[2][4] = {};
  {
    int j0 = js * 1024;
#pragma unroll
    for (int p = 0; p < 2; ++p) {
      int ck = wave * 2 + p;
      int jm = ck >> 1, ks = ck & 1;
      load_lds16(&kb[(size_t)(j0 + jm * 16 + ln) * HD + ks * 32 + quad * 8], &sK[0][ck * 512]);
      load_lds16(&vtb[(size_t)(jm * 16 + ln) * LL + j0 + ks * 32 + quad * 8], &sV[0][ck * 512]);
    }
  }
  for (int jt = 0; jt < 16; ++jt) {
    int cur = jt & 1;
    __syncthreads();   // vmcnt(0) drain -> buf[cur] complete; fences buf[cur^1] readers
    if (jt + 1 < 16) {
      int j0n = js * 1024 + (jt + 1) * 64;
#pragma unroll
      for (int p = 0; p < 2; ++p) {
        int ck = wave * 2 + p;
        int jm = ck >> 1, ks = ck & 1;
        load_lds16(&kb[(size_t)(j0n + jm * 16 + ln) * HD + ks * 32 + quad * 8],
                   &sK[cur ^ 1][ck * 512]);
        load_lds16(&vtb[(size_t)(jm * 16 + ln) * LL + j0n + ks * 32 + quad * 8],
                   &sV[cur ^ 1][ck * 512]);
      }
    }
    const unsigned short* sKc = sK[cur];
    const unsigned short* sVc = sV[cur];
    floatx4 st[4][2] = {};
#pragma unroll
    for (int ks = 0; ks < 2; ++ks)
#pragma unroll
      for (int jm = 0; jm < 4; ++jm) {
        short8 ak = *(const short8*)&sKc[(jm * 2 + ks) * 512 + lane * 8];
        st[jm][0] = __builtin_amdgcn_mfma_f32_16x16x32_bf16(ak, qfrag[0][ks], st[jm][0], 0, 0, 0);
        st[jm][1] = __builtin_amdgcn_mfma_f32_16x16x32_bf16(ak, qfrag[1][ks], st[jm][1], 0, 0, 0);
      }
#pragma unroll
    for (int si = 0; si < 2; ++si)
#pragma unroll
      for (int jm = 0; jm < 4; ++jm) {
        float e0 = EXP2(st[jm][si][0]);
        float e1 = EXP2(st[jm][si][1]);
        float e2 = EXP2(st[jm][si][2]);
        float e3 = EXP2(st[jm][si][3]);
        l[si] += (e0 + e1) + (e2 + e3);
        uint2 pk;
        pk.x = pack2bf(e0, e1);
        pk.y = pack2bf(e2, e3);
        int elem = (si * 2 + (jm >> 1)) * 512 +
                   (((jm & 1) * 2 + (quad >> 1)) * 16 + ln) * 8 + (quad & 1) * 4;
        *(uint2*)&sPw[elem] = pk;
      }
#pragma unroll
    for (int ks = 0; ks < 2; ++ks) {
      short8 ap0 = *(const short8*)&sPw[(0 * 2 + ks) * 512 + lane * 8];
      short8 ap1 = *(const short8*)&sPw[(1 * 2 + ks) * 512 + lane * 8];
#pragma unroll
      for (int nt = 0; nt < 4; ++nt) {
        short8 bv = *(const short8*)&sVc[(nt * 2 + ks) * 512 + lane * 8];
        oacc[0][nt] = __builtin_amdgcn_mfma_f32_16x16x32_bf16(ap0, bv, oacc[0][nt], 0, 0, 0);
        oacc[1][nt] = __builtin_amdgcn_mfma_f32_16x16x32_bf16(ap1, bv, oacc[1][nt], 0, 0, 0);
      }
    }
  }
#pragma unroll
  for (int si = 0; si < 2; ++si) {
    l[si] += __shfl_xor(l[si], 16, 64);
    l[si] += __shfl_xor(l[si], 32, 64);
  }
  float* op = opart + (size_t)js * M_TOT * DIM;
  if (quad == 0) {
#pragma unroll
    for (int si = 0; si < 2; ++si)
      lpart[((size_t)js * BB * NHEADS + bh) * LL + i0 + iw0 + si * 16 + ln] = l[si];
  }
#pragma unroll
  for (int si = 0; si < 2; ++si)
#pragma unroll
    for (int r = 0; r < 4; ++r) {
      int row = i0 + iw0 + si * 16 + quad * 4 + r;
#pragma unroll
      for (int nt = 0; nt < 4; ++nt) {
        int d = nt * 16 + ln;
        op[((size_t)(b * LL + row)) * DIM + h * HD + d] = oacc[si][nt][r];
      }
    }
}

extern "C" void kernel_launch(void* const* d_in, const int* in_sizes, int n_in,
                              void* d_out, int out_size, void* d_ws, size_t ws_size,
                              hipStream_t stream) {
  (void)in_sizes; (void)n_in; (void)out_size; (void)ws_size;
  const float* x = (const float*)d_in[0];
  const float* Wqkv = (const float*)d_in[1];
  const float* bqkv = (const float*)d_in[2];
  const float* Wproj = (const float*)d_in[3];
  const float* bproj = (const float*)d_in[4];
  float* out = (float*)d_out;

  char* ws = (char*)d_ws;
  size_t off = 0;
  unsigned short* wqkv_t  = (unsigned short*)(ws + off); off += (size_t)NQKV * DIM * 2;
  unsigned short* wproj_t = (unsigned short*)(ws + off); off += (size_t)DIM * DIM * 2;
  unsigned short* qbuf    = (unsigned short*)(ws + off); off += (size_t)BB * NHEADS * LL * HD * 2;
  unsigned short* kbuf    = (unsigned short*)(ws + off); off += (size_t)BB * NHEADS * LL * HD * 2;
  unsigned short* vtbuf   = (unsigned short*)(ws + off); off += (size_t)BB * NHEADS * LL * HD * 2;
  float*          opart   = (float*)(ws + off);          off += (size_t)2 * M_TOT * DIM * 4;
  float*          lpart   = (float*)(ws + off);          off += (size_t)2 * BB * NHEADS * LL * 4;

  prep_kernel<<<dim3(2304), 256, 0, stream>>>(Wqkv, Wproj, wqkv_t, wproj_t);
  gemm_kernel<64, 128, 0><<<dim3((M_TOT / 64) * (NQKV / 128)), 256, 0, stream>>>(
      x, wqkv_t, bqkv, nullptr, qbuf, kbuf, vtbuf, nullptr);
  flash11_kernel<<<dim3((LL / 128) * 24 * 2), 256, 0, stream>>>(qbuf, kbuf, vtbuf, opart, lpart);
  gemm_kernel<64, 64, 1><<<dim3((M_TOT / 64) * (DIM / 64)), 256, 0, stream>>>(
      opart, wproj_t, bproj, out, nullptr, nullptr, nullptr, lpart);
}

// Round 13
// 185.273 us; speedup vs baseline: 1.0869x; 1.0869x over previous
//
#include <hip/hip_runtime.h>
#include <math.h>

#define DIM 768
#define NHEADS 12
#define HD 64
#define BB 2
#define LL 2048
#define M_TOT (BB*LL)      /* 4096 */
#define NQKV (3*DIM)       /* 2304 */
#define QSCALE 0.18033688011112042f  /* 0.125 * log2(e) */

typedef __attribute__((ext_vector_type(8))) short short8;
typedef __attribute__((ext_vector_type(4))) float floatx4;

__device__ __forceinline__ unsigned short f2bf(float f) {
  unsigned int u = __float_as_uint(f);
  u += 0x7fff + ((u >> 16) & 1);   // round-to-nearest-even
  return (unsigned short)(u >> 16);
}

#if __has_builtin(__builtin_amdgcn_cvt_pk_bf16_f32)
typedef __attribute__((ext_vector_type(2))) __bf16 bf16x2_t;
__device__ __forceinline__ unsigned int pack2bf(float a, float b) {
  bf16x2_t r = __builtin_amdgcn_cvt_pk_bf16_f32(a, b);   // lo=a, hi=b, RNE
  return *(unsigned int*)&r;
}
#else
__device__ __forceinline__ unsigned int pack2bf(float a, float b) {
  unsigned int ua = __float_as_uint(a) + 0x8000u;
  unsigned int ub = __float_as_uint(b) + 0x8000u;
  return (ub & 0xffff0000u) | (ua >> 16);
}
#endif

// bare v_exp_f32 (scores bounded, no denormal/NaN risk) — avoids OCML fixups
#if __has_builtin(__builtin_amdgcn_exp2f)
#define EXP2(x) __builtin_amdgcn_exp2f(x)
#else
#define EXP2(x) exp2f(x)
#endif

// async global->LDS DMA, 16B/lane; LDS dst = wave-uniform base + lane*16
__device__ __forceinline__ void load_lds16(const unsigned short* g, unsigned short* l) {
  __builtin_amdgcn_global_load_lds(
      (const __attribute__((address_space(1))) unsigned int*)g,
      (__attribute__((address_space(3))) unsigned int*)l, 16, 0, 0);
}

// ---- prep: transpose-cast BOTH weights in one launch ----
__global__ void prep_kernel(const float* __restrict__ Wqkv, const float* __restrict__ Wproj,
                            unsigned short* __restrict__ wqkv_t,
                            unsigned short* __restrict__ wproj_t) {
  __shared__ float tl[32][33];
  int bx = blockIdx.x;
  const float* src; unsigned short* dst; int C, r0, c0;
  if (bx < 1728) { src = Wqkv;  dst = wqkv_t;  C = NQKV; c0 = (bx % 72) * 32; r0 = (bx / 72) * 32; }
  else { int b2 = bx - 1728; src = Wproj; dst = wproj_t; C = DIM; c0 = (b2 % 24) * 32; r0 = (b2 / 24) * 32; }
  int t = threadIdx.x;
  int tr = t >> 3, tc = (t & 7) * 4;
  float4 v = *(const float4*)&src[(size_t)(r0 + tr) * C + c0 + tc];
  tl[tr][tc] = v.x; tl[tr][tc + 1] = v.y; tl[tr][tc + 2] = v.z; tl[tr][tc + 3] = v.w;
  __syncthreads();
  int oc = t >> 3, orr = (t & 7) * 4;
  ushort4 o;
  o.x = f2bf(tl[orr][oc]); o.y = f2bf(tl[orr + 1][oc]);
  o.z = f2bf(tl[orr + 2][oc]); o.w = f2bf(tl[orr + 3][oc]);
  *(ushort4*)&dst[(size_t)(c0 + oc) * 768 + r0 + orr] = o;
}

// ---- 128x128-tile bf16 MFMA GEMM, K=768, padded LDS (R11-verified, 53.4us) ----
// Inner loop / staging / fusions UNTOUCHED. Tile-shape space exhausted:
// TM=64 regressed 3x (R7/R12: amortization loss > residency gain). 128x128 is
// this structure's optimum (~271 TF, consistent with m102 shape curve).
// MODE 0: A = x fp32 (cast fused); scatters q (pre-scaled), k, V^T. Grid 576.
// MODE 1: A = opart (combine fused, h == kt); SPLIT-K=2: split = bx/192 does
//         k-tiles [split*6, split*6+6), writes fp32 partial (NO bias) to
//         outf + split*M*N. Grid 384 = 1.5 blocks/CU vs 0.75 — residency 2x
//         with the 128-tile amortization intact (unlike the TM=64 failures).
template<int MODE>
__global__ __launch_bounds__(256) void gemm128_kernel(
    const float* __restrict__ Af, const unsigned short* __restrict__ Bt,
    const float* __restrict__ bias, float* __restrict__ outf,
    unsigned short* __restrict__ qb, unsigned short* __restrict__ kb,
    unsigned short* __restrict__ vtb, const float* __restrict__ lpart) {
  __shared__ unsigned short sA[128 * 72];
  __shared__ unsigned short sB[128 * 72];
  int t = threadIdx.x;
  int bx = blockIdx.x;
  int split = (MODE == 1) ? (bx / 192) : 0;
  int bxl = (MODE == 1) ? (bx % 192) : bx;
  int m0 = (bxl % 32) * 128, n0 = (bxl / 32) * 128;
  int kt0 = split * 6, kt1 = kt0 + ((MODE == 1) ? 6 : 12);
  int wave = t >> 6, lane = t & 63, ln = lane & 15, quad = lane >> 4;
  int wm = (wave >> 1) * 64, wn = (wave & 1) * 64;
  floatx4 acc[4][4] = {};
  for (int kt = kt0; kt < kt1; ++kt) {
    __syncthreads();
#pragma unroll
    for (int p = 0; p < 4; ++p) {
      int u = t + p * 256;
      int row = u >> 3, c = (u & 7) * 8;
      uint4 pk;
      if (MODE == 0) {
        const float* s = &Af[(size_t)(m0 + row) * 768 + kt * 64 + c];
        float4 v0 = *(const float4*)s, v1 = *(const float4*)(s + 4);
        pk.x = pack2bf(v0.x, v0.y); pk.y = pack2bf(v0.z, v0.w);
        pk.z = pack2bf(v1.x, v1.y); pk.w = pack2bf(v1.z, v1.w);
      } else {
        int gr = m0 + row;
        const float* s0 = &Af[(size_t)gr * 768 + kt * 64 + c];
        const float* s1 = s0 + (size_t)M_TOT * DIM;
        float4 a0 = *(const float4*)s0, a1 = *(const float4*)(s0 + 4);
        float4 b0 = *(const float4*)s1, b1 = *(const float4*)(s1 + 4);
        int bb = gr >> 11, ii = gr & 2047, bh = bb * NHEADS + kt;   // h == kt
        float inv = 1.0f / (lpart[(size_t)bh * LL + ii] +
                            lpart[(size_t)(BB * NHEADS + bh) * LL + ii]);
        pk.x = pack2bf((a0.x + b0.x) * inv, (a0.y + b0.y) * inv);
        pk.y = pack2bf((a0.z + b0.z) * inv, (a0.w + b0.w) * inv);
        pk.z = pack2bf((a1.x + b1.x) * inv, (a1.y + b1.y) * inv);
        pk.w = pack2bf((a1.z + b1.z) * inv, (a1.w + b1.w) * inv);
      }
      *(uint4*)&sA[row * 72 + c] = pk;
      *(uint4*)&sB[row * 72 + c] = *(const uint4*)&Bt[(size_t)(n0 + row) * 768 + kt * 64 + c];
    }
    __syncthreads();
#pragma unroll
    for (int ks = 0; ks < 2; ++ks) {
      short8 af[4], bfr[4];
#pragma unroll
      for (int s = 0; s < 4; ++s) {
        af[s]  = *(const short8*)&sA[(wm + s * 16 + ln) * 72 + ks * 32 + quad * 8];
        bfr[s] = *(const short8*)&sB[(wn + s * 16 + ln) * 72 + ks * 32 + quad * 8];
      }
#pragma unroll
      for (int i = 0; i < 4; ++i)
#pragma unroll
        for (int j = 0; j < 4; ++j)
          acc[i][j] = __builtin_amdgcn_mfma_f32_16x16x32_bf16(af[i], bfr[j], acc[i][j], 0, 0, 0);
    }
  }
#pragma unroll
  for (int mt = 0; mt < 4; ++mt)
#pragma unroll
    for (int nt = 0; nt < 4; ++nt)
#pragma unroll
      for (int r = 0; r < 4; ++r) {
        int row = m0 + wm + mt * 16 + quad * 4 + r;   // C/D: col=lane&15, row=quad*4+reg
        int col = n0 + wn + nt * 16 + ln;
        if (MODE == 0) {
          float val = acc[mt][nt][r] + bias[col];
          int which = (col >= 1536) ? 2 : (col >= 768) ? 1 : 0;
          int rem = col - which * 768;
          int h = rem >> 6, d = rem & 63;
          int b = row >> 11, i = row & 2047;
          int bh = b * NHEADS + h;
          if (which == 0) qb[((size_t)bh * LL + i) * HD + d] = f2bf(val * QSCALE);
          else if (which == 1) kb[((size_t)bh * LL + i) * HD + d] = f2bf(val);
          else vtb[((size_t)bh * HD + d) * LL + i] = f2bf(val);   // transposed V
        } else {
          outf[(size_t)split * M_TOT * DIM + (size_t)row * 768 + col] = acc[mt][nt][r];
        }
      }
}

// ---- reduce: out = p0 + p1 + bias (fp32), one float4 per thread ----
__global__ void reduce_kernel(const float* __restrict__ pbuf,
                              const float* __restrict__ bias,
                              float* __restrict__ out) {
  int idx = blockIdx.x * blockDim.x + threadIdx.x;
  int base = idx * 4;
  int col = base % DIM;
  float4 p0 = *(const float4*)&pbuf[base];
  float4 p1 = *(const float4*)&pbuf[(size_t)M_TOT * DIM + base];
  float4 bi = *(const float4*)&bias[col];
  float4 o;
  o.x = p0.x + p1.x + bi.x;
  o.y = p0.y + p1.y + bi.y;
  o.z = p0.z + p1.z + bi.z;
  o.w = p0.w + p1.w + bi.w;
  *(float4*)&out[base] = o;
}

// ---------------- flash attention v11 (R11-verified, unchanged) ----------------
__global__ __launch_bounds__(256, 3) void flash11_kernel(
    const unsigned short* __restrict__ q, const unsigned short* __restrict__ k,
    const unsigned short* __restrict__ vt, float* __restrict__ opart,
    float* __restrict__ lpart) {
  __shared__ unsigned short sK[2][8 * 512];
  __shared__ unsigned short sV[2][8 * 512];
  __shared__ unsigned short sP[4][4 * 512];
  int t = threadIdx.x;
  int wave = t >> 6, lane = t & 63, ln = lane & 15, quad = lane >> 4;
  int bx = blockIdx.x;
  int bhjs = bx % 48;
  int i0 = (bx / 48) * 128;
  int bh = bhjs >> 1, js = bhjs & 1;
  int b = bh / NHEADS, h = bh % NHEADS;
  const unsigned short* qb = q + (size_t)bh * LL * HD;
  const unsigned short* kb = k + (size_t)bh * LL * HD;
  const unsigned short* vtb = vt + (size_t)bh * HD * LL;
  int iw0 = wave * 32;
  short8 qfrag[2][2];
#pragma unroll
  for (int si = 0; si < 2; ++si)
#pragma unroll
    for (int ks = 0; ks < 2; ++ks)
      qfrag[si][ks] = *(const short8*)&qb[(size_t)(i0 + iw0 + si * 16 + ln) * HD + ks * 32 + quad * 8];
  unsigned short* sPw = sP[wave];
  float l[2] = {0.f, 0.f};
  floatx4 oacc[2][4] = {};
  {
    int j0 = js * 1024;
#pragma unroll
    for (int p = 0; p < 2; ++p) {
      int ck = wave * 2 + p;
      int jm = ck >> 1, ks = ck & 1;
      load_lds16(&kb[(size_t)(j0 + jm * 16 + ln) * HD + ks * 32 + quad * 8], &sK[0][ck * 512]);
      load_lds16(&vtb[(size_t)(jm * 16 + ln) * LL + j0 + ks * 32 + quad * 8], &sV[0][ck * 512]);
    }
  }
  for (int jt = 0; jt < 16; ++jt) {
    int cur = jt & 1;
    __syncthreads();   // vmcnt(0) drain -> buf[cur] complete; fences buf[cur^1] readers
    if (jt + 1 < 16) {
      int j0n = js * 1024 + (jt + 1) * 64;
#pragma unroll
      for (int p = 0; p < 2; ++p) {
        int ck = wave * 2 + p;
        int jm = ck >> 1, ks = ck & 1;
        load_lds16(&kb[(size_t)(j0n + jm * 16 + ln) * HD + ks * 32 + quad * 8],
                   &sK[cur ^ 1][ck * 512]);
        load_lds16(&vtb[(size_t)(jm * 16 + ln) * LL + j0n + ks * 32 + quad * 8],
                   &sV[cur ^ 1][ck * 512]);
      }
    }
    const unsigned short* sKc = sK[cur];
    const unsigned short* sVc = sV[cur];
    floatx4 st[4][2] = {};
#pragma unroll
    for (int ks = 0; ks < 2; ++ks)
#pragma unroll
      for (int jm = 0; jm < 4; ++jm) {
        short8 ak = *(const short8*)&sKc[(jm * 2 + ks) * 512 + lane * 8];
        st[jm][0] = __builtin_amdgcn_mfma_f32_16x16x32_bf16(ak, qfrag[0][ks], st[jm][0], 0, 0, 0);
        st[jm][1] = __builtin_amdgcn_mfma_f32_16x16x32_bf16(ak, qfrag[1][ks], st[jm][1], 0, 0, 0);
      }
#pragma unroll
    for (int si = 0; si < 2; ++si)
#pragma unroll
      for (int jm = 0; jm < 4; ++jm) {
        float e0 = EXP2(st[jm][si][0]);
        float e1 = EXP2(st[jm][si][1]);
        float e2 = EXP2(st[jm][si][2]);
        float e3 = EXP2(st[jm][si][3]);
        l[si] += (e0 + e1) + (e2 + e3);
        uint2 pk;
        pk.x = pack2bf(e0, e1);
        pk.y = pack2bf(e2, e3);
        int elem = (si * 2 + (jm >> 1)) * 512 +
                   (((jm & 1) * 2 + (quad >> 1)) * 16 + ln) * 8 + (quad & 1) * 4;
        *(uint2*)&sPw[elem] = pk;
      }
#pragma unroll
    for (int ks = 0; ks < 2; ++ks) {
      short8 ap0 = *(const short8*)&sPw[(0 * 2 + ks) * 512 + lane * 8];
      short8 ap1 = *(const short8*)&sPw[(1 * 2 + ks) * 512 + lane * 8];
#pragma unroll
      for (int nt = 0; nt < 4; ++nt) {
        short8 bv = *(const short8*)&sVc[(nt * 2 + ks) * 512 + lane * 8];
        oacc[0][nt] = __builtin_amdgcn_mfma_f32_16x16x32_bf16(ap0, bv, oacc[0][nt], 0, 0, 0);
        oacc[1][nt] = __builtin_amdgcn_mfma_f32_16x16x32_bf16(ap1, bv, oacc[1][nt], 0, 0, 0);
      }
    }
  }
#pragma unroll
  for (int si = 0; si < 2; ++si) {
    l[si] += __shfl_xor(l[si], 16, 64);
    l[si] += __shfl_xor(l[si], 32, 64);
  }
  float* op = opart + (size_t)js * M_TOT * DIM;
  if (quad == 0) {
#pragma unroll
    for (int si = 0; si < 2; ++si)
      lpart[((size_t)js * BB * NHEADS + bh) * LL + i0 + iw0 + si * 16 + ln] = l[si];
  }
#pragma unroll
  for (int si = 0; si < 2; ++si)
#pragma unroll
    for (int r = 0; r < 4; ++r) {
      int row = i0 + iw0 + si * 16 + quad * 4 + r;
#pragma unroll
      for (int nt = 0; nt < 4; ++nt) {
        int d = nt * 16 + ln;
        op[((size_t)(b * LL + row)) * DIM + h * HD + d] = oacc[si][nt][r];
      }
    }
}

extern "C" void kernel_launch(void* const* d_in, const int* in_sizes, int n_in,
                              void* d_out, int out_size, void* d_ws, size_t ws_size,
                              hipStream_t stream) {
  (void)in_sizes; (void)n_in; (void)out_size; (void)ws_size;
  const float* x = (const float*)d_in[0];
  const float* Wqkv = (const float*)d_in[1];
  const float* bqkv = (const float*)d_in[2];
  const float* Wproj = (const float*)d_in[3];
  const float* bproj = (const float*)d_in[4];
  float* out = (float*)d_out;

  char* ws = (char*)d_ws;
  size_t off = 0;
  unsigned short* wqkv_t  = (unsigned short*)(ws + off); off += (size_t)NQKV * DIM * 2;
  unsigned short* wproj_t = (unsigned short*)(ws + off); off += (size_t)DIM * DIM * 2;
  unsigned short* qbuf    = (unsigned short*)(ws + off); off += (size_t)BB * NHEADS * LL * HD * 2;
  unsigned short* kbuf    = (unsigned short*)(ws + off); off += (size_t)BB * NHEADS * LL * HD * 2;
  unsigned short* vtbuf   = (unsigned short*)(ws + off); off += (size_t)BB * NHEADS * LL * HD * 2;
  float*          opart   = (float*)(ws + off);          off += (size_t)2 * M_TOT * DIM * 4;
  float*          lpart   = (float*)(ws + off);          off += (size_t)2 * BB * NHEADS * LL * 4;
  float*          pbuf    = (float*)(ws + off);          off += (size_t)2 * M_TOT * DIM * 4;

  prep_kernel<<<dim3(2304), 256, 0, stream>>>(Wqkv, Wproj, wqkv_t, wproj_t);
  gemm128_kernel<0><<<dim3(32 * (NQKV / 128)), 256, 0, stream>>>(
      x, wqkv_t, bqkv, nullptr, qbuf, kbuf, vtbuf, nullptr);
  flash11_kernel<<<dim3((LL / 128) * 24 * 2), 256, 0, stream>>>(qbuf, kbuf, vtbuf, opart, lpart);
  gemm128_kernel<1><<<dim3(2 * 192), 256, 0, stream>>>(
      opart, wproj_t, nullptr, pbuf, nullptr, nullptr, nullptr, lpart);
  reduce_kernel<<<dim3((M_TOT * DIM) / (256 * 4)), 256, 0, stream>>>(pbuf, bproj, out);
}